// Round 6
// baseline (304.086 us; speedup 1.0000x reference)
//
#include <hip/hip_runtime.h>
#include <math.h>

// MoE: T=4096, D=1024, H=2048, O=1024, E=8, top-2.
// Routed sparse, flat-slot tiling: 8192 slots = 64 row-tiles of 128 exactly.
// GEMMs: per-wave 64x64 (acc=64 regs -> 4 waves/EU -> 2-4 blocks/CU
// co-resident), BK=32, 2-phase loop, chunk-XOR swizzle, XCD panel affinity
// (bid%8 = nt). Boundary tiles (expert change inside tile) run a 2nd pass.

#define T_TOK 4096
#define DIM   1024
#define HID   2048
#define OUTD  1024
#define NE    8

typedef __bf16 bf16_t;
typedef __bf16 bf16x8 __attribute__((ext_vector_type(8)));
typedef float  f32x4  __attribute__((ext_vector_type(4)));

typedef __attribute__((address_space(3))) void       as3_void;
typedef __attribute__((address_space(1))) const void as1_void;
#define GLDS16(src, dst) \
  __builtin_amdgcn_global_load_lds((as1_void*)(src), (as3_void*)(dst), 16, 0, 0)

// ------- gating: logits (fp32 lane-partials, fp64 reduce), top-2, x->bf16 ---
__global__ void k_gate(const float* __restrict__ x, const float* __restrict__ Wg,
                       const float* __restrict__ bg, int* __restrict__ einfo,
                       float2* __restrict__ gpair, bf16_t* __restrict__ xb) {
  int wid  = threadIdx.x >> 6;
  int lane = threadIdx.x & 63;
  int t = blockIdx.x * 4 + wid;

  const float4* xr = (const float4*)(x + (size_t)t * DIM);
  float4 xv4[4];
  float sf[NE];
#pragma unroll
  for (int e = 0; e < NE; ++e) sf[e] = 0.f;

#pragma unroll
  for (int i = 0; i < 4; ++i) {
    int q = lane + 64 * i;
    float4 xv = xr[q];
    xv4[i] = xv;
    int d = q * 4;
#pragma unroll
    for (int c = 0; c < 4; ++c) {
      float xc = (&xv.x)[c];
      const float4* wr = (const float4*)(Wg + (size_t)(d + c) * NE);
      float4 w0 = wr[0], w1 = wr[1];
      sf[0] += xc * w0.x; sf[1] += xc * w0.y;
      sf[2] += xc * w0.z; sf[3] += xc * w0.w;
      sf[4] += xc * w1.x; sf[5] += xc * w1.y;
      sf[6] += xc * w1.z; sf[7] += xc * w1.w;
    }
  }

  ushort4* xbr = (ushort4*)(xb + (size_t)t * DIM);
#pragma unroll
  for (int i = 0; i < 4; ++i) {
    union { bf16_t b[4]; ushort4 u; } cv;
    cv.b[0] = (bf16_t)xv4[i].x; cv.b[1] = (bf16_t)xv4[i].y;
    cv.b[2] = (bf16_t)xv4[i].z; cv.b[3] = (bf16_t)xv4[i].w;
    xbr[lane + 64 * i] = cv.u;
  }

  double s[NE];
#pragma unroll
  for (int e = 0; e < NE; ++e) s[e] = (double)sf[e];
#pragma unroll
  for (int off = 32; off > 0; off >>= 1) {
#pragma unroll
    for (int e = 0; e < NE; ++e) s[e] += __shfl_xor(s[e], off);
  }

  if (lane == 0) {
    double v0 = -1e300, v1 = -1e300;
    int i0 = 0, i1 = 0;
#pragma unroll
    for (int e = 0; e < NE; ++e) {
      double v = s[e] + (double)bg[e];
      if (v > v0)      { v1 = v0; i1 = i0; v0 = v; i0 = e; }
      else if (v > v1) { v1 = v;  i1 = e; }
    }
    float ex = expf((float)(v1 - v0));
    float inv = 1.0f / (1.0f + ex);
    einfo[t] = i0 | (i1 << 8);
    gpair[t] = make_float2(inv, ex * inv);
  }
}

// ------- binning: ballot stream-compaction, wave w = expert w ---------------
__global__ void k_bin(const int* __restrict__ einfo, const float2* __restrict__ gpair,
                      int* __restrict__ cnt, int* __restrict__ offs,
                      int* __restrict__ elist, float* __restrict__ egate,
                      int* __restrict__ tokrec) {
  __shared__ int scnt[NE];
  int w = threadIdx.x >> 6;
  int lane = threadIdx.x & 63;
  unsigned long long below = (lane == 0) ? 0ull : ((~0ull) >> (64 - lane));
  int base = 0;
  for (int c = 0; c < T_TOK / 64; ++c) {
    int t = c * 64 + lane;
    int ei = einfo[t];
    float2 g = gpair[t];
    int e0 = ei & 0xff, e1 = ei >> 8;
    bool m0 = (e0 == w);
    bool m  = m0 || (e1 == w);
    unsigned long long mask = __ballot(m);
    if (m) {
      int pos = base + (int)__popcll(mask & below);
      elist[w * T_TOK + pos] = t;
      egate[w * T_TOK + pos] = m0 ? g.x : g.y;
      tokrec[2 * t + (m0 ? 0 : 1)] = (w << 16) | pos;
    }
    base += (int)__popcll(mask);
  }
  if (lane == 0) scnt[w] = base;
  __syncthreads();
  if (threadIdx.x == 0) {
    int a = 0;
#pragma unroll
    for (int e = 0; e < NE; ++e) {
      cnt[e] = scnt[e];
      offs[e] = a;
      a += scnt[e];
    }
    offs[NE] = a;
  }
}

// ------------- per-expert transpose + convert: W[R][C] -> Wt[C][R] bf16 -----
__global__ void k_tr(const float* __restrict__ W, bf16_t* __restrict__ Wt,
                     int R, int C) {
  __shared__ float tile[32][33];
  size_t ebase = (size_t)blockIdx.z * R * C;
  int c0 = blockIdx.x * 32, r0 = blockIdx.y * 32;
  int id = threadIdx.x;
  int rc = id >> 5, cc = id & 31;
#pragma unroll
  for (int i = 0; i < 4; ++i)
    tile[rc + i * 8][cc] = W[ebase + (size_t)(r0 + rc + i * 8) * C + c0 + cc];
  __syncthreads();
  int oc = id >> 4, orp = id & 15;
  ushort2* wt2 = (ushort2*)(Wt + ebase);
#pragma unroll
  for (int i = 0; i < 2; ++i) {
    int c = oc + i * 16;
    union { bf16_t b[2]; ushort2 u; } cv;
    cv.b[0] = (bf16_t)tile[orp * 2][c];
    cv.b[1] = (bf16_t)tile[orp * 2 + 1][c];
    wt2[((size_t)(c0 + c) * R + r0 + orp * 2) >> 1] = cv.u;
  }
}

// Swizzle for BK=32 (row = 64 B = 4 chunks): chunk' = chunk ^ ((row>>1)&3).
// 8 consecutive rows occupy 8 distinct 16B LDS slots -> 2-way max (free).

// ---------------- GEMM1: h = relu(gather(x) @ W1 + b1) ----------------------
// Tile 128x256, BK=32, 8 waves (2x4), per-wave 64x64. LDS 48 KB, 2 blocks/CU.
// grid 512: nt = bid&7 (XCD panel affinity), rt = bid>>3 (flat row tile).
__launch_bounds__(512, 4)
__global__ void k_gemm1(const bf16_t* __restrict__ xb, const bf16_t* __restrict__ W1t,
                        const float* __restrict__ b1, const int* __restrict__ offs,
                        const int* __restrict__ elist, bf16_t* __restrict__ hbuf) {
  const int bid = blockIdx.x;
  const int nt = bid & 7, rt = bid >> 3;
  const int r0 = rt * 128;

  __shared__ __align__(16) char smem[49152];

  const int tid = threadIdx.x, lane = tid & 63, wid = tid >> 6;
  const int wm = wid >> 2, wn = wid & 3;
  const int fr = lane & 15, lh = lane >> 4;

  // ---- A staging source (pass-independent, gathered): chunk = tid ----
  const int ra = tid >> 2, cca = tid & 3;
  const int ska = cca ^ ((ra >> 1) & 3);
  const int sA = r0 + ra;
  int eA = 0;
  while (offs[eA + 1] <= sA) ++eA;
  const int tokA = elist[eA * T_TOK + sA - offs[eA]];
  const char* srcA = (const char*)xb + ((size_t)tokA * DIM + ska * 8) * 2;

  // ---- B staging rows (per-pass base): chunks tid, tid+512 ----
  const int rb0 = tid >> 2, ccb0 = tid & 3;
  const int skb0 = ccb0 ^ ((rb0 >> 1) & 3);
  const int rb1 = (tid + 512) >> 2, ccb1 = tid & 3;
  const int skb1 = ccb1 ^ ((rb1 >> 1) & 3);

  // ---- ds_read addrs (slot-local, swizzled) ----
  unsigned rdA[4], rdB[4];
#pragma unroll
  for (int mi = 0; mi < 4; ++mi) {
    int r = wm * 64 + mi * 16 + fr;
    rdA[mi] = (unsigned)(r * 64 + ((lh ^ ((r >> 1) & 3)) * 16));
  }
#pragma unroll
  for (int nj = 0; nj < 4; ++nj) {
    int r = wn * 64 + nj * 16 + fr;
    rdB[nj] = (unsigned)(r * 64 + ((lh ^ ((r >> 1) & 3)) * 16));
  }

  const int NT = DIM / 32;  // 32

  // ---- pass loop over experts overlapping [r0, r0+128) ----
  int e = 0;
  while (offs[e + 1] <= r0) ++e;
  for (;;) {
    const int lo = offs[e] > r0 ? offs[e] : r0;
    const int hi = offs[e + 1] < r0 + 128 ? offs[e + 1] : r0 + 128;

    const char* srcB0 = (const char*)W1t +
        ((size_t)(e * HID + nt * 256 + rb0) * DIM + skb0 * 8) * 2;
    const char* srcB1 = (const char*)W1t +
        ((size_t)(e * HID + nt * 256 + rb1) * DIM + skb1 * 8) * 2;

    f32x4 acc[4][4];
#pragma unroll
    for (int i = 0; i < 4; ++i)
#pragma unroll
      for (int j = 0; j < 4; ++j) acc[i][j] = (f32x4){0.f, 0.f, 0.f, 0.f};

    // prologue
    GLDS16(srcA, smem + tid * 16);
    GLDS16(srcB0, smem + 16384 + tid * 16);
    GLDS16(srcB1, smem + 16384 + (512 + tid) * 16);
    __syncthreads();

#pragma unroll 2
    for (int t = 0; t < NT; ++t) {
      if (t + 1 < NT) {
        char* da = smem + ((t + 1) & 1) * 8192;
        char* db = smem + 16384 + ((t + 1) & 1) * 16384;
        GLDS16(srcA + (t + 1) * 64, da + tid * 16);
        GLDS16(srcB0 + (t + 1) * 64, db + tid * 16);
        GLDS16(srcB1 + (t + 1) * 64, db + (512 + tid) * 16);
      }
      const char* a_ = smem + (t & 1) * 8192;
      const char* b_ = smem + 16384 + (t & 1) * 16384;
      bf16x8 af[4], bf[4];
#pragma unroll
      for (int mi = 0; mi < 4; ++mi) af[mi] = *(const bf16x8*)(a_ + rdA[mi]);
#pragma unroll
      for (int nj = 0; nj < 4; ++nj) bf[nj] = *(const bf16x8*)(b_ + rdB[nj]);
#pragma unroll
      for (int mi = 0; mi < 4; ++mi)
#pragma unroll
        for (int nj = 0; nj < 4; ++nj)
          acc[mi][nj] = __builtin_amdgcn_mfma_f32_16x16x32_bf16(
              af[mi], bf[nj], acc[mi][nj], 0, 0, 0);
      __syncthreads();
    }

    // epilogue: rows (flat slots) in [lo, hi)
#pragma unroll
    for (int mi = 0; mi < 4; ++mi) {
#pragma unroll
      for (int rr = 0; rr < 4; ++rr) {
        int row = r0 + wm * 64 + mi * 16 + lh * 4 + rr;
        if (row >= lo && row < hi) {
          size_t hrow = (size_t)row * HID;
#pragma unroll
          for (int nj = 0; nj < 4; ++nj) {
            int col = nt * 256 + wn * 64 + nj * 16 + fr;
            float v = acc[mi][nj][rr] + b1[e * HID + col];
            hbuf[hrow + col] = (bf16_t)(v > 0.f ? v : 0.f);
          }
        }
      }
    }

    if (hi >= r0 + 128) break;
    ++e;
  }
}

// ---------------- GEMM2: y[slot] = gate * (h @ W2 + b2) ---------------------
// Tile 128x128, BK=32, 4 waves (2x2), per-wave 64x64. LDS 32 KB, 4 blocks/CU.
__launch_bounds__(256, 4)
__global__ void k_gemm2(const bf16_t* __restrict__ hbuf, const bf16_t* __restrict__ W2t,
                        const float* __restrict__ b2, const int* __restrict__ offs,
                        const float* __restrict__ egate, float* __restrict__ y) {
  const int bid = blockIdx.x;
  const int nt = bid & 7, rt = bid >> 3;
  const int r0 = rt * 128;

  __shared__ __align__(16) char smem[32768];

  const int tid = threadIdx.x, lane = tid & 63, wid = tid >> 6;
  const int wm = wid >> 1, wn = wid & 1;
  const int fr = lane & 15, lh = lane >> 4;

  // A: 512 chunks -> 2/thread (flat slots, no gather)
  const int ra0 = tid >> 2,          ska0 = (tid & 3) ^ ((ra0 >> 1) & 3);
  const int ra1 = (tid + 256) >> 2,  ska1 = (tid & 3) ^ ((ra1 >> 1) & 3);
  const char* srcA0 = (const char*)hbuf + ((size_t)(r0 + ra0) * HID + ska0 * 8) * 2;
  const char* srcA1 = (const char*)hbuf + ((size_t)(r0 + ra1) * HID + ska1 * 8) * 2;

  const int rb0 = tid >> 2,          skb0 = (tid & 3) ^ ((rb0 >> 1) & 3);
  const int rb1 = (tid + 256) >> 2,  skb1 = (tid & 3) ^ ((rb1 >> 1) & 3);

  unsigned rdA[4], rdB[4];
#pragma unroll
  for (int mi = 0; mi < 4; ++mi) {
    int r = wm * 64 + mi * 16 + fr;
    rdA[mi] = (unsigned)(r * 64 + ((lh ^ ((r >> 1) & 3)) * 16));
  }
#pragma unroll
  for (int nj = 0; nj < 4; ++nj) {
    int r = wn * 64 + nj * 16 + fr;
    rdB[nj] = (unsigned)(r * 64 + ((lh ^ ((r >> 1) & 3)) * 16));
  }

  const int NT = HID / 32;  // 64

  int e = 0;
  while (offs[e + 1] <= r0) ++e;
  for (;;) {
    const int lo = offs[e] > r0 ? offs[e] : r0;
    const int hi = offs[e + 1] < r0 + 128 ? offs[e + 1] : r0 + 128;

    const char* srcB0 = (const char*)W2t +
        ((size_t)(e * OUTD + nt * 128 + rb0) * HID + skb0 * 8) * 2;
    const char* srcB1 = (const char*)W2t +
        ((size_t)(e * OUTD + nt * 128 + rb1) * HID + skb1 * 8) * 2;

    f32x4 acc[4][4];
#pragma unroll
    for (int i = 0; i < 4; ++i)
#pragma unroll
      for (int j = 0; j < 4; ++j) acc[i][j] = (f32x4){0.f, 0.f, 0.f, 0.f};

    GLDS16(srcA0, smem + tid * 16);
    GLDS16(srcA1, smem + (256 + tid) * 16);
    GLDS16(srcB0, smem + 16384 + tid * 16);
    GLDS16(srcB1, smem + 16384 + (256 + tid) * 16);
    __syncthreads();

#pragma unroll 2
    for (int t = 0; t < NT; ++t) {
      if (t + 1 < NT) {
        char* da = smem + ((t + 1) & 1) * 8192;
        char* db = smem + 16384 + ((t + 1) & 1) * 8192;
        GLDS16(srcA0 + (t + 1) * 64, da + tid * 16);
        GLDS16(srcA1 + (t + 1) * 64, da + (256 + tid) * 16);
        GLDS16(srcB0 + (t + 1) * 64, db + tid * 16);
        GLDS16(srcB1 + (t + 1) * 64, db + (256 + tid) * 16);
      }
      const char* a_ = smem + (t & 1) * 8192;
      const char* b_ = smem + 16384 + (t & 1) * 8192;
      bf16x8 af[4], bf[4];
#pragma unroll
      for (int mi = 0; mi < 4; ++mi) af[mi] = *(const bf16x8*)(a_ + rdA[mi]);
#pragma unroll
      for (int nj = 0; nj < 4; ++nj) bf[nj] = *(const bf16x8*)(b_ + rdB[nj]);
#pragma unroll
      for (int mi = 0; mi < 4; ++mi)
#pragma unroll
        for (int nj = 0; nj < 4; ++nj)
          acc[mi][nj] = __builtin_amdgcn_mfma_f32_16x16x32_bf16(
              af[mi], bf[nj], acc[mi][nj], 0, 0, 0);
      __syncthreads();
    }

#pragma unroll
    for (int mi = 0; mi < 4; ++mi) {
#pragma unroll
      for (int rr = 0; rr < 4; ++rr) {
        int row = r0 + wm * 64 + mi * 16 + lh * 4 + rr;
        if (row >= lo && row < hi) {
          float gate = egate[e * T_TOK + row - offs[e]];
          size_t yrow = (size_t)row * OUTD;
#pragma unroll
          for (int nj = 0; nj < 4; ++nj) {
            int col = nt * 128 + wn * 64 + nj * 16 + fr;
            y[yrow + col] = gate * (acc[mi][nj][rr] + b2[e * OUTD + col]);
          }
        }
      }
    }

    if (hi >= r0 + 128) break;
    ++e;
  }
}

// ---------------- combine: out[t] = y[slot0] + y[slot1] ---------------------
__global__ void k_combine(const float* __restrict__ y, const int* __restrict__ offs,
                          const int* __restrict__ tokrec, float* __restrict__ out) {
  int t = blockIdx.x;
  int r0 = tokrec[2 * t], r1 = tokrec[2 * t + 1];
  int s0 = offs[r0 >> 16] + (r0 & 0xffff);
  int s1 = offs[r1 >> 16] + (r1 & 0xffff);
  const float4* ya = (const float4*)(y + (size_t)s0 * OUTD);
  const float4* yb = (const float4*)(y + (size_t)s1 * OUTD);
  float4* o = (float4*)(out + (size_t)t * OUTD);
  int i = threadIdx.x;
  float4 a = ya[i], b = yb[i];
  o[i] = make_float4(a.x + b.x, a.y + b.y, a.z + b.z, a.w + b.w);
}

// ---------------------------------------------------------------------------
extern "C" void kernel_launch(void* const* d_in, const int* in_sizes, int n_in,
                              void* d_out, int out_size, void* d_ws, size_t ws_size,
                              hipStream_t stream) {
  const float* x  = (const float*)d_in[0];
  const float* Wg = (const float*)d_in[1];
  const float* bg = (const float*)d_in[2];
  const float* W1 = (const float*)d_in[3];
  const float* b1 = (const float*)d_in[4];
  const float* W2 = (const float*)d_in[5];
  const float* b2 = (const float*)d_in[6];
  float* out = (float*)d_out;

  char* ws = (char*)d_ws;
  int*    cnt    = (int*)(ws);
  int*    offs   = (int*)(ws + 1024);
  int*    tokrec = (int*)(ws + 4096);                       // 32 KB
  int*    einfo  = (int*)(ws + 36864);                      // 16 KB
  float2* gpair  = (float2*)(ws + 53248);                   // 32 KB
  int*    elist  = (int*)(ws + 131072);                     // 128 KB
  float*  egate  = (float*)(ws + 262144);                   // 128 KB
  bf16_t* W1t    = (bf16_t*)(ws + (1u << 20));              // 32 MB
  float*  y      = (float*)(ws + (1u << 20));               // aliases W1t (dead by gemm2)
  bf16_t* W2t    = (bf16_t*)(ws + (1u << 20) + (32u << 20));// 32 MB
  bf16_t* xb     = (bf16_t*)(ws + (1u << 20) + (64u << 20));// 8 MB
  bf16_t* hbuf   = (bf16_t*)(ws + (1u << 20) + (72u << 20));// 32 MB

  k_gate<<<T_TOK / 4, 256, 0, stream>>>(x, Wg, bg, einfo, gpair, xb);
  k_bin<<<1, 512, 0, stream>>>(einfo, gpair, cnt, offs, elist, egate, tokrec);
  k_tr<<<dim3(HID / 32, DIM / 32, NE), 256, 0, stream>>>(W1, W1t, DIM, HID);
  k_tr<<<dim3(OUTD / 32, HID / 32, NE), 256, 0, stream>>>(W2, W2t, HID, OUTD);

  k_gemm1<<<512, 512, 0, stream>>>(xb, W1t, b1, offs, elist, hbuf);
  k_gemm2<<<512, 256, 0, stream>>>(hbuf, W2t, b2, offs, egate, y);
  k_combine<<<T_TOK, 256, 0, stream>>>(y, offs, tokrec, out);
}

// Round 7
// 230.825 us; speedup vs baseline: 1.3174x; 1.3174x over previous
//
#include <hip/hip_runtime.h>
#include <math.h>

// MoE: T=4096, D=1024, H=2048, O=1024, E=8, top-2.
// Routed sparse: 68.7 GFLOP bf16 MFMA. GEMMs use 256x256/BK=64 8-wave 8-phase
// schedule (T2 chunk-XOR swizzle + T3/T4 counted vmcnt + T5 setprio) with
// REGISTER FRAGMENT REUSE: A-frags read at Q0/Q2 (reused by adjacent phase),
// B-frags read at Q0/Q1 (held through Q2/Q3). LDS reads per K-tile per wave
// 48 -> 24 x b128 (phase loop was LDS-read-bound at ~96 KB/phase).

#define T_TOK 4096
#define DIM   1024
#define HID   2048
#define OUTD  1024
#define NE    8

typedef __bf16 bf16_t;
typedef __bf16 bf16x8 __attribute__((ext_vector_type(8)));
typedef float  f32x4  __attribute__((ext_vector_type(4)));

typedef __attribute__((address_space(3))) void       as3_void;
typedef __attribute__((address_space(1))) const void as1_void;
#define GLDS16(src, dst) \
  __builtin_amdgcn_global_load_lds((as1_void*)(src), (as3_void*)(dst), 16, 0, 0)

#define FENCE() asm volatile("" ::: "memory")
#define BARRIER() do { FENCE(); __builtin_amdgcn_s_barrier(); FENCE(); } while (0)

// ------- gating: logits (fp32 lane-partials, fp64 reduce), top-2, x->bf16 ---
__global__ void k_gate(const float* __restrict__ x, const float* __restrict__ Wg,
                       const float* __restrict__ bg, int* __restrict__ einfo,
                       float2* __restrict__ gpair, bf16_t* __restrict__ xb) {
  int wid  = threadIdx.x >> 6;
  int lane = threadIdx.x & 63;
  int t = blockIdx.x * 4 + wid;

  const float4* xr = (const float4*)(x + (size_t)t * DIM);
  float4 xv4[4];
  float sf[NE];
#pragma unroll
  for (int e = 0; e < NE; ++e) sf[e] = 0.f;

#pragma unroll
  for (int i = 0; i < 4; ++i) {
    int q = lane + 64 * i;
    float4 xv = xr[q];
    xv4[i] = xv;
    int d = q * 4;
#pragma unroll
    for (int c = 0; c < 4; ++c) {
      float xc = (&xv.x)[c];
      const float4* wr = (const float4*)(Wg + (size_t)(d + c) * NE);
      float4 w0 = wr[0], w1 = wr[1];
      sf[0] += xc * w0.x; sf[1] += xc * w0.y;
      sf[2] += xc * w0.z; sf[3] += xc * w0.w;
      sf[4] += xc * w1.x; sf[5] += xc * w1.y;
      sf[6] += xc * w1.z; sf[7] += xc * w1.w;
    }
  }

  ushort4* xbr = (ushort4*)(xb + (size_t)t * DIM);
#pragma unroll
  for (int i = 0; i < 4; ++i) {
    union { bf16_t b[4]; ushort4 u; } cv;
    cv.b[0] = (bf16_t)xv4[i].x; cv.b[1] = (bf16_t)xv4[i].y;
    cv.b[2] = (bf16_t)xv4[i].z; cv.b[3] = (bf16_t)xv4[i].w;
    xbr[lane + 64 * i] = cv.u;
  }

  double s[NE];
#pragma unroll
  for (int e = 0; e < NE; ++e) s[e] = (double)sf[e];
#pragma unroll
  for (int off = 32; off > 0; off >>= 1) {
#pragma unroll
    for (int e = 0; e < NE; ++e) s[e] += __shfl_xor(s[e], off);
  }

  if (lane == 0) {
    double v0 = -1e300, v1 = -1e300;
    int i0 = 0, i1 = 0;
#pragma unroll
    for (int e = 0; e < NE; ++e) {
      double v = s[e] + (double)bg[e];
      if (v > v0)      { v1 = v0; i1 = i0; v0 = v; i0 = e; }
      else if (v > v1) { v1 = v;  i1 = e; }
    }
    float ex = expf((float)(v1 - v0));
    float inv = 1.0f / (1.0f + ex);
    einfo[t] = i0 | (i1 << 8);
    gpair[t] = make_float2(inv, ex * inv);
  }
}

// ------- binning: ballot stream-compaction, wave w = expert w ---------------
__global__ void k_bin(const int* __restrict__ einfo, const float2* __restrict__ gpair,
                      int* __restrict__ cnt, int* __restrict__ offs,
                      int* __restrict__ elist, float* __restrict__ egate,
                      int* __restrict__ tokrec) {
  __shared__ int scnt[NE];
  int w = threadIdx.x >> 6;
  int lane = threadIdx.x & 63;
  unsigned long long below = (lane == 0) ? 0ull : ((~0ull) >> (64 - lane));
  int base = 0;
  for (int c = 0; c < T_TOK / 64; ++c) {
    int t = c * 64 + lane;
    int ei = einfo[t];
    float2 g = gpair[t];
    int e0 = ei & 0xff, e1 = ei >> 8;
    bool m0 = (e0 == w);
    bool m  = m0 || (e1 == w);
    unsigned long long mask = __ballot(m);
    if (m) {
      int pos = base + (int)__popcll(mask & below);
      elist[w * T_TOK + pos] = t;
      egate[w * T_TOK + pos] = m0 ? g.x : g.y;
      tokrec[2 * t + (m0 ? 0 : 1)] = (w << 16) | pos;
    }
    base += (int)__popcll(mask);
  }
  if (lane == 0) scnt[w] = base;
  __syncthreads();
  if (threadIdx.x == 0) {
    int a = 0;
#pragma unroll
    for (int e = 0; e < NE; ++e) {
      cnt[e] = scnt[e];
      offs[e] = a;
      a += scnt[e];
    }
    offs[NE] = a;
  }
}

// ------------- per-expert transpose + convert: W[R][C] -> Wt[C][R] bf16 -----
__global__ void k_tr(const float* __restrict__ W, bf16_t* __restrict__ Wt,
                     int R, int C) {
  __shared__ float tile[32][33];
  size_t ebase = (size_t)blockIdx.z * R * C;
  int c0 = blockIdx.x * 32, r0 = blockIdx.y * 32;
  int id = threadIdx.x;
  int rc = id >> 5, cc = id & 31;
#pragma unroll
  for (int i = 0; i < 4; ++i)
    tile[rc + i * 8][cc] = W[ebase + (size_t)(r0 + rc + i * 8) * C + c0 + cc];
  __syncthreads();
  int oc = id >> 4, orp = id & 15;
  ushort2* wt2 = (ushort2*)(Wt + ebase);
#pragma unroll
  for (int i = 0; i < 2; ++i) {
    int c = oc + i * 16;
    union { bf16_t b[2]; ushort2 u; } cv;
    cv.b[0] = (bf16_t)tile[orp * 2][c];
    cv.b[1] = (bf16_t)tile[orp * 2 + 1][c];
    wt2[((size_t)(c0 + c) * R + r0 + orp * 2) >> 1] = cv.u;
  }
}

// ---------------- 8-phase 256x256 GEMM machinery ----------------------------
// LDS: A half-slots at smem + ((buf*2+half)<<14), B at +65536. Slot = 128x64 bf16.
// Chunk-XOR swizzle on global source + ds_read addr (both-sides involution).

#define STAGE_A(TT, HH) do { \
    char* _d = smem + ((((TT) & 1) * 2 + (HH)) << 14); \
    GLDS16(Abase + offA[HH][0] + (TT) * 128, _d + dstq0 * 16); \
    GLDS16(Abase + offA[HH][1] + (TT) * 128, _d + dstq1 * 16); } while (0)

#define STAGE_B(TT, HH) do { \
    char* _d = smem + 65536 + ((((TT) & 1) * 2 + (HH)) << 14); \
    GLDS16(Bbase + offB[HH][0] + (TT) * 128, _d + dstq0 * 16); \
    GLDS16(Bbase + offB[HH][1] + (TT) * 128, _d + dstq1 * 16); } while (0)

#define MFMA_Q(AF, BF, AH, BH) \
    _Pragma("unroll") for (int i = 0; i < 4; ++i) \
      _Pragma("unroll") for (int j = 0; j < 2; ++j) \
        _Pragma("unroll") for (int kk = 0; kk < 2; ++kk) \
          acc[(AH) * 4 + i][(BH) * 2 + j] = \
            __builtin_amdgcn_mfma_f32_16x16x32_bf16(AF[i][kk], BF[j][kk], \
                acc[(AH) * 4 + i][(BH) * 2 + j], 0, 0, 0)

#define LGKM_WAIT() do { \
    asm volatile("s_waitcnt lgkmcnt(0)" ::: "memory"); \
    __builtin_amdgcn_sched_barrier(0); } while (0)

// One K-tile = 4 phases. A-frags read at Q0 (half0) / Q2 (half1), reused by
// the adjacent phase. B-frags read at Q0 (half0) / Q1 (half1), held to Q2/Q3.
#define KTILE(TT, NTc) do { \
    const char* _a0 = smem + ((((TT) & 1) * 2 + 0) << 14); \
    const char* _a1 = smem + ((((TT) & 1) * 2 + 1) << 14); \
    const char* _b0 = smem + 65536 + ((((TT) & 1) * 2 + 0) << 14); \
    const char* _b1 = smem + 65536 + ((((TT) & 1) * 2 + 1) << 14); \
    bf16x8 af[4][2], bf0[2][2], bf1[2][2]; \
    /* Q0: (Ah0 x Bh0) */ \
    _Pragma("unroll") for (int i = 0; i < 4; ++i) \
      _Pragma("unroll") for (int kk = 0; kk < 2; ++kk) \
        af[i][kk] = *(const bf16x8*)(_a0 + rdA[i][kk]); \
    _Pragma("unroll") for (int j = 0; j < 2; ++j) \
      _Pragma("unroll") for (int kk = 0; kk < 2; ++kk) \
        bf0[j][kk] = *(const bf16x8*)(_b0 + rdB[j][kk]); \
    if ((TT) + 1 < (NTc)) STAGE_A((TT) + 1, 1); \
    BARRIER(); LGKM_WAIT(); \
    __builtin_amdgcn_s_setprio(1); MFMA_Q(af, bf0, 0, 0); \
    __builtin_amdgcn_s_setprio(0); BARRIER(); \
    /* Q1: (Ah0 x Bh1), A reused */ \
    _Pragma("unroll") for (int j = 0; j < 2; ++j) \
      _Pragma("unroll") for (int kk = 0; kk < 2; ++kk) \
        bf1[j][kk] = *(const bf16x8*)(_b1 + rdB[j][kk]); \
    if ((TT) + 1 < (NTc)) STAGE_B((TT) + 1, 1); \
    BARRIER(); LGKM_WAIT(); \
    __builtin_amdgcn_s_setprio(1); MFMA_Q(af, bf1, 0, 1); \
    __builtin_amdgcn_s_setprio(0); BARRIER(); \
    /* Q2: (Ah1 x Bh0), B held */ \
    _Pragma("unroll") for (int i = 0; i < 4; ++i) \
      _Pragma("unroll") for (int kk = 0; kk < 2; ++kk) \
        af[i][kk] = *(const bf16x8*)(_a1 + rdA[i][kk]); \
    if ((TT) + 2 < (NTc)) STAGE_A((TT) + 2, 0); \
    BARRIER(); LGKM_WAIT(); \
    __builtin_amdgcn_s_setprio(1); MFMA_Q(af, bf0, 1, 0); \
    __builtin_amdgcn_s_setprio(0); BARRIER(); \
    /* Q3: (Ah1 x Bh1), A+B held, no ds_reads */ \
    if ((TT) + 2 < (NTc)) { STAGE_B((TT) + 2, 0); \
      asm volatile("s_waitcnt vmcnt(4)" ::: "memory"); } \
    else { asm volatile("s_waitcnt vmcnt(0)" ::: "memory"); } \
    BARRIER(); \
    __builtin_amdgcn_s_setprio(1); MFMA_Q(af, bf1, 1, 1); \
    __builtin_amdgcn_s_setprio(0); BARRIER(); \
  } while (0)

// ---------------- GEMM1: h = relu(gather(x) @ W1 + b1) ----------------------
__launch_bounds__(512, 2)
__global__ void k_gemm1(const bf16_t* __restrict__ xb, const bf16_t* __restrict__ W1t,
                        const float* __restrict__ b1, const int* __restrict__ cnt,
                        const int* __restrict__ offs, const int* __restrict__ elist,
                        bf16_t* __restrict__ hbuf) {
  const int e = blockIdx.z;
  const int count = cnt[e];
  const int rt = blockIdx.y;
  if (rt * 256 >= count) return;
  const int nt = blockIdx.x;

  __shared__ __align__(16) char smem[131072];

  const int tid = threadIdx.x, lane = tid & 63, wid = tid >> 6;
  const int wm = wid >> 2, wn = wid & 3;
  const int fr = lane & 15, lh = lane >> 4;

  unsigned offA[2][2], offB[2][2];
  const int dstq0 = tid, dstq1 = 512 + tid;
#pragma unroll
  for (int j = 0; j < 2; ++j) {
    int q = j * 512 + tid;
    int r = q >> 3, sfg = (q & 7) ^ (r & 7);
#pragma unroll
    for (int h = 0; h < 2; ++h) {
      int gr = rt * 256 + h * 128 + r;
      if (gr > count - 1) gr = count - 1;
      int tok = elist[e * T_TOK + gr];
      offA[h][j] = (unsigned)((tok * DIM + sfg * 8) * 2);
      int brow = nt * 256 + h * 128 + r;
      offB[h][j] = (unsigned)(((e * HID + brow) * DIM + sfg * 8) * 2);
    }
  }
  unsigned rdA[4][2], rdB[2][2];
#pragma unroll
  for (int i = 0; i < 4; ++i) {
    int r = wm * 64 + i * 16 + fr;
#pragma unroll
    for (int kk = 0; kk < 2; ++kk)
      rdA[i][kk] = (unsigned)(r * 128 + (((kk * 4 + lh) ^ (r & 7)) * 16));
  }
#pragma unroll
  for (int j = 0; j < 2; ++j) {
    int r = wn * 32 + j * 16 + fr;
#pragma unroll
    for (int kk = 0; kk < 2; ++kk)
      rdB[j][kk] = (unsigned)(r * 128 + (((kk * 4 + lh) ^ (r & 7)) * 16));
  }

  const char* Abase = (const char*)xb;
  const char* Bbase = (const char*)W1t;

  f32x4 acc[8][4];
#pragma unroll
  for (int i = 0; i < 8; ++i)
#pragma unroll
    for (int j = 0; j < 4; ++j) acc[i][j] = (f32x4){0.f, 0.f, 0.f, 0.f};

  const int NT = DIM / 64;  // 16
  STAGE_A(0, 0); STAGE_B(0, 0); STAGE_A(0, 1); STAGE_B(0, 1);
  STAGE_A(1, 0); STAGE_B(1, 0);
  asm volatile("s_waitcnt vmcnt(4)" ::: "memory");
  BARRIER();

  for (int t = 0; t < NT; ++t) KTILE(t, NT);

  const int hbase = offs[e];
#pragma unroll
  for (int mi = 0; mi < 8; ++mi) {
#pragma unroll
    for (int rr = 0; rr < 4; ++rr) {
      int rowp = rt * 256 + (mi >> 2) * 128 + wm * 64 + (mi & 3) * 16 + lh * 4 + rr;
      if (rowp < count) {
        size_t hrow = (size_t)(hbase + rowp) * HID;
#pragma unroll
        for (int nj = 0; nj < 4; ++nj) {
          int col = nt * 256 + (nj >> 1) * 128 + wn * 32 + (nj & 1) * 16 + fr;
          float v = acc[mi][nj][rr] + b1[e * HID + col];
          hbuf[hrow + col] = (bf16_t)(v > 0.f ? v : 0.f);
        }
      }
    }
  }
}

// ---------------- GEMM2: y[slot] = gate * (h @ W2 + b2) ---------------------
__launch_bounds__(512, 2)
__global__ void k_gemm2(const bf16_t* __restrict__ hbuf, const bf16_t* __restrict__ W2t,
                        const float* __restrict__ b2, const int* __restrict__ cnt,
                        const int* __restrict__ offs, const float* __restrict__ egate,
                        float* __restrict__ y) {
  const int e = blockIdx.z;
  const int count = cnt[e];
  const int rt = blockIdx.y;
  if (rt * 256 >= count) return;
  const int nt = blockIdx.x;

  __shared__ __align__(16) char smem[131072];

  const int tid = threadIdx.x, lane = tid & 63, wid = tid >> 6;
  const int wm = wid >> 2, wn = wid & 3;
  const int fr = lane & 15, lh = lane >> 4;
  const int hbase = offs[e];

  unsigned offA[2][2], offB[2][2];
  const int dstq0 = tid, dstq1 = 512 + tid;
#pragma unroll
  for (int j = 0; j < 2; ++j) {
    int q = j * 512 + tid;
    int r = q >> 3, sfg = (q & 7) ^ (r & 7);
#pragma unroll
    for (int h = 0; h < 2; ++h) {
      int gr = rt * 256 + h * 128 + r;
      if (gr > count - 1) gr = count - 1;
      offA[h][j] = (unsigned)(((hbase + gr) * HID + sfg * 8) * 2);
      int brow = nt * 256 + h * 128 + r;
      offB[h][j] = (unsigned)(((e * OUTD + brow) * HID + sfg * 8) * 2);
    }
  }
  unsigned rdA[4][2], rdB[2][2];
#pragma unroll
  for (int i = 0; i < 4; ++i) {
    int r = wm * 64 + i * 16 + fr;
#pragma unroll
    for (int kk = 0; kk < 2; ++kk)
      rdA[i][kk] = (unsigned)(r * 128 + (((kk * 4 + lh) ^ (r & 7)) * 16));
  }
#pragma unroll
  for (int j = 0; j < 2; ++j) {
    int r = wn * 32 + j * 16 + fr;
#pragma unroll
    for (int kk = 0; kk < 2; ++kk)
      rdB[j][kk] = (unsigned)(r * 128 + (((kk * 4 + lh) ^ (r & 7)) * 16));
  }

  const char* Abase = (const char*)hbuf;
  const char* Bbase = (const char*)W2t;

  f32x4 acc[8][4];
#pragma unroll
  for (int i = 0; i < 8; ++i)
#pragma unroll
    for (int j = 0; j < 4; ++j) acc[i][j] = (f32x4){0.f, 0.f, 0.f, 0.f};

  const int NT = HID / 64;  // 32
  STAGE_A(0, 0); STAGE_B(0, 0); STAGE_A(0, 1); STAGE_B(0, 1);
  STAGE_A(1, 0); STAGE_B(1, 0);
  asm volatile("s_waitcnt vmcnt(4)" ::: "memory");
  BARRIER();

  for (int t = 0; t < NT; ++t) KTILE(t, NT);

#pragma unroll
  for (int mi = 0; mi < 8; ++mi) {
#pragma unroll
    for (int rr = 0; rr < 4; ++rr) {
      int rowp = rt * 256 + (mi >> 2) * 128 + wm * 64 + (mi & 3) * 16 + lh * 4 + rr;
      if (rowp < count) {
        float gate = egate[e * T_TOK + rowp];
        size_t yrow = (size_t)(hbase + rowp) * OUTD;
#pragma unroll
        for (int nj = 0; nj < 4; ++nj) {
          int col = nt * 256 + (nj >> 1) * 128 + wn * 32 + (nj & 1) * 16 + fr;
          y[yrow + col] = gate * (acc[mi][nj][rr] + b2[e * OUTD + col]);
        }
      }
    }
  }
}

// ---------------- combine: out[t] = y[slot0] + y[slot1] ---------------------
__global__ void k_combine(const float* __restrict__ y, const int* __restrict__ offs,
                          const int* __restrict__ tokrec, float* __restrict__ out) {
  int t = blockIdx.x;
  int r0 = tokrec[2 * t], r1 = tokrec[2 * t + 1];
  int s0 = offs[r0 >> 16] + (r0 & 0xffff);
  int s1 = offs[r1 >> 16] + (r1 & 0xffff);
  const float4* ya = (const float4*)(y + (size_t)s0 * OUTD);
  const float4* yb = (const float4*)(y + (size_t)s1 * OUTD);
  float4* o = (float4*)(out + (size_t)t * OUTD);
  int i = threadIdx.x;
  float4 a = ya[i], b = yb[i];
  o[i] = make_float4(a.x + b.x, a.y + b.y, a.z + b.z, a.w + b.w);
}

// ---------------------------------------------------------------------------
extern "C" void kernel_launch(void* const* d_in, const int* in_sizes, int n_in,
                              void* d_out, int out_size, void* d_ws, size_t ws_size,
                              hipStream_t stream) {
  const float* x  = (const float*)d_in[0];
  const float* Wg = (const float*)d_in[1];
  const float* bg = (const float*)d_in[2];
  const float* W1 = (const float*)d_in[3];
  const float* b1 = (const float*)d_in[4];
  const float* W2 = (const float*)d_in[5];
  const float* b2 = (const float*)d_in[6];
  float* out = (float*)d_out;

  char* ws = (char*)d_ws;
  int*    cnt    = (int*)(ws);
  int*    offs   = (int*)(ws + 1024);
  int*    tokrec = (int*)(ws + 4096);                       // 32 KB
  int*    einfo  = (int*)(ws + 36864);                      // 16 KB
  float2* gpair  = (float2*)(ws + 53248);                   // 32 KB
  int*    elist  = (int*)(ws + 131072);                     // 128 KB
  float*  egate  = (float*)(ws + 262144);                   // 128 KB
  bf16_t* W1t    = (bf16_t*)(ws + (1u << 20));              // 32 MB
  float*  y      = (float*)(ws + (1u << 20));               // aliases W1t (dead by gemm2)
  bf16_t* W2t    = (bf16_t*)(ws + (1u << 20) + (32u << 20));// 32 MB
  bf16_t* xb     = (bf16_t*)(ws + (1u << 20) + (64u << 20));// 8 MB
  bf16_t* hbuf   = (bf16_t*)(ws + (1u << 20) + (72u << 20));// 32 MB

  k_gate<<<T_TOK / 4, 256, 0, stream>>>(x, Wg, bg, einfo, gpair, xb);
  k_bin<<<1, 512, 0, stream>>>(einfo, gpair, cnt, offs, elist, egate, tokrec);
  k_tr<<<dim3(HID / 32, DIM / 32, NE), 256, 0, stream>>>(W1, W1t, DIM, HID);
  k_tr<<<dim3(OUTD / 32, HID / 32, NE), 256, 0, stream>>>(W2, W2t, HID, OUTD);

  k_gemm1<<<dim3(HID / 256, 16, NE), 512, 0, stream>>>(
      xb, W1t, b1, cnt, offs, elist, hbuf);
  k_gemm2<<<dim3(OUTD / 256, 16, NE), 512, 0, stream>>>(
      hbuf, W2t, b2, cnt, offs, egate, y);
  k_combine<<<T_TOK, 256, 0, stream>>>(y, offs, tokrec, out);
}